// Round 8
// baseline (203.608 us; speedup 1.0000x reference)
//
#include <hip/hip_runtime.h>

#define DEVI __device__ __forceinline__

typedef __bf16 v8bf __attribute__((ext_vector_type(8)));
typedef float  v4f  __attribute__((ext_vector_type(4)));
typedef short  v4s  __attribute__((ext_vector_type(4)));

DEVI unsigned short f2bf(float f) {
  unsigned u = __builtin_bit_cast(unsigned, f);
  u += 0x7fffu + ((u >> 16) & 1u);
  return (unsigned short)(u >> 16);
}
DEVI v4f MFMA32(v8bf a, v8bf b, v4f c) {
  return __builtin_amdgcn_mfma_f32_16x16x32_bf16(a, b, c, 0, 0, 0);
}
DEVI v8bf ldfrag(const unsigned short* p) {
  return __builtin_bit_cast(v8bf, *(const uint4*)p);
}
DEVI v4s ld4s(const unsigned short* p) {
  return __builtin_bit_cast(v4s, *(const uint2*)p);
}
// pack two floats -> two bf16 in one dword (round-half-up + v_perm)
DEVI unsigned pkbf(float lo, float hi) {
  unsigned a = __builtin_bit_cast(unsigned, hi) + 0x8000u;
  unsigned b = __builtin_bit_cast(unsigned, lo) + 0x8000u;
  return __builtin_amdgcn_perm(a, b, 0x07060302u);
}
DEVI float lo2f(unsigned u) { return __builtin_bit_cast(float, u << 16); }
DEVI float hi2f(unsigned u) { return __builtin_bit_cast(float, u & 0xffff0000u); }

#if __has_builtin(__builtin_amdgcn_exp2f)
DEVI float fexp2(float x) { return __builtin_amdgcn_exp2f(x); }
#else
DEVI float fexp2(float x) { return exp2f(x); }
#endif

#if __has_builtin(__builtin_amdgcn_mfma_f32_16x16x16bf16_1k)
#define HAVE_MFMA16 1
DEVI v4f MFMA16(v4s a, v4s b, v4f c) {
  return __builtin_amdgcn_mfma_f32_16x16x16bf16_1k(a, b, c, 0, 0, 0);
}
#else
#define HAVE_MFMA16 0
#endif

// async global->LDS, 16B per lane; per-lane global addresses pre-apply the
// XOR swizzle (LDS side must stay contiguous).
#if __has_builtin(__builtin_amdgcn_global_load_lds)
DEVI void g2l(const unsigned short* g, unsigned short* l) {
  __builtin_amdgcn_global_load_lds(
      (const __attribute__((address_space(1))) unsigned int*)g,
      (__attribute__((address_space(3))) unsigned int*)l, 16, 0, 0);
}
#else
DEVI void g2l(const unsigned short* g, unsigned short* l) {
  *(uint4*)((char*)l + (threadIdx.x & 63) * 16) = *(const uint4*)g;
}
#endif

// ---------------------------------------------------------------------------
// fp32 -> bf16 conversion of X (4,2,1024,512) and Wq/Wk/Wv/Wo (512x512 each).
// ---------------------------------------------------------------------------
__global__ __launch_bounds__(256) void convert_kernel(
    const float* __restrict__ X, const float* __restrict__ Wq,
    const float* __restrict__ Wk, const float* __restrict__ Wv,
    const float* __restrict__ Wo, unsigned short* __restrict__ dst)
{
  int t = blockIdx.x * 256 + threadIdx.x;
  int idx = t * 4;
  const float* src;
  if (idx < 4194304) {
    src = X + idx;
  } else {
    int u = idx - 4194304;
    int w = u >> 18;
    const float* W = (w == 0) ? Wq : (w == 1) ? Wk : (w == 2) ? Wv : Wo;
    src = W + (u & 262143);
  }
  float4 f = *(const float4*)src;
  uint2 o;
  o.x = pkbf(f.x, f.y);
  o.y = pkbf(f.z, f.w);
  *(uint2*)&dst[idx] = o;
}

// ---------------------------------------------------------------------------
// C[m][n] = sum_k A[m][k]*W[n][k] + bias[n]   (BT GEMM, M=8192 N=512 K=512)
// BMx128 tile, 4 waves, global_load_lds staging, XOR-swizzled LDS.
// OUTM=0 bf16 out (z==2 -> V transposed into VT);  OUTM=1 fp32 out.
// ---------------------------------------------------------------------------
template<int OUTM, int BM>
__global__ __launch_bounds__(256) void gemm_bt(
    const unsigned short* __restrict__ A,
    const unsigned short* __restrict__ W0, const unsigned short* __restrict__ W1,
    const unsigned short* __restrict__ W2,
    const float* __restrict__ b0, const float* __restrict__ b1, const float* __restrict__ b2,
    void* __restrict__ C0, void* __restrict__ C1, void* __restrict__ C2)
{
  const int K = 512, N = 512;
  const int MI = BM / 32;
  const int PER = (BM / 8 + 16) / 4;          // g2l chunks per wave
  __shared__ unsigned short sAB[(BM + 128) * 64];
  const int z = blockIdx.z;
  const unsigned short* W = (z == 0) ? W0 : (z == 1) ? W1 : W2;
  const float* bias = (z == 0) ? b0 : (z == 1) ? b1 : b2;
  void* C = (z == 0) ? C0 : (z == 1) ? C1 : C2;

  const int tid = threadIdx.x;
  const int lane = tid & 63, wave = tid >> 6;
  const int l15 = lane & 15, quad = lane >> 4, swl = l15 & 7;
  const int lrow = lane >> 3;
  const int lc8 = ((lane & 7) ^ (lrow & 7)) * 8;
  const int wm = (wave >> 1) * (BM / 2), wn = (wave & 1) * 64;
  const int mbase = blockIdx.y * BM, nbase = blockIdx.x * 128;

  const unsigned short* gsrc[PER];
  unsigned short* ldst[PER];
#pragma unroll
  for (int t = 0; t < PER; t++) {
    int c = wave * PER + t;
    ldst[t] = &sAB[c * 512];
    if (c < BM / 8) gsrc[t] = A + (size_t)(mbase + c * 8 + lrow) * K + lc8;
    else            gsrc[t] = W + (size_t)(nbase + (c - BM / 8) * 8 + lrow) * K + lc8;
  }

  v4f acc[MI][4] = {};

  for (int kt = 0; kt < K; kt += 64) {
    __syncthreads();
#pragma unroll
    for (int t = 0; t < PER; t++) g2l(gsrc[t] + kt, ldst[t]);
    __syncthreads();
#pragma unroll
    for (int s = 0; s < 2; s++) {
      v8bf af[MI], bf[4];
#pragma unroll
      for (int i = 0; i < MI; i++)
        af[i] = ldfrag(&sAB[(wm + i * 16 + l15) * 64 + ((s * 4 + quad) ^ swl) * 8]);
#pragma unroll
      for (int j = 0; j < 4; j++)
        bf[j] = ldfrag(&sAB[(BM + wn + j * 16 + l15) * 64 + ((s * 4 + quad) ^ swl) * 8]);
#pragma unroll
      for (int i = 0; i < MI; i++)
#pragma unroll
        for (int j = 0; j < 4; j++)
          acc[i][j] = MFMA32(af[i], bf[j], acc[i][j]);
    }
  }

#pragma unroll
  for (int i = 0; i < MI; i++)
#pragma unroll
    for (int j = 0; j < 4; j++) {
      int row0 = mbase + wm + i * 16 + quad * 4;
      int col = nbase + wn + j * 16 + l15;
      float v[4];
#pragma unroll
      for (int r = 0; r < 4; r++) v[r] = acc[i][j][r] + bias[col];
      if (OUTM == 1) {
#pragma unroll
        for (int r = 0; r < 4; r++) ((float*)C)[(size_t)(row0 + r) * N + col] = v[r];
      } else if (z == 2) {
        int bs = row0 >> 10, t0 = row0 & 1023;
        int hh = col >> 6, hd = col & 63;
        uint2 o;
        o.x = pkbf(v[0], v[1]);
        o.y = pkbf(v[2], v[3]);
        *(uint2*)&((unsigned short*)C)[(size_t)((bs * 8 + hh) * 64 + hd) * 1024 + t0] = o;
      } else {
#pragma unroll
        for (int r = 0; r < 4; r++)
          ((unsigned short*)C)[(size_t)(row0 + r) * N + col] = f2bf(v[r]);
      }
    }
}

// ---------------------------------------------------------------------------
// Fused competitive cross-attention — k-split, no-exchange-in-hot-loop.
// Grid 512 x 512 threads (8 waves).  Block = (b,h,64-q-row tile).
// wave -> (qg = wave&3 : 16 q rows, kh = wave>>2 : 512-key half), BOTH dirs
// per wave -> competitive combine in-register via sigmoid:
//   r0 = 1/(1+exp2((s1-s0)*S2 + ll0-ll1))   (eps droppable: p~1e-3 >> 1e-6)
// 8 LDS tiles/iter (2 kh x 2 stream x {K,V}), one tile staged per wave via
// global_load_lds, XOR-swizzled.  Pass A partial l-sums merged via sL;
// partial oacc merged once at the end via sT reuse.  LDS 65 KB, 2 blk/CU,
// 4 waves/SIMD.
// ---------------------------------------------------------------------------
__global__ __launch_bounds__(512, 4) void attn_kernel(
    const unsigned short* __restrict__ Qg, const unsigned short* __restrict__ Kg,
    const unsigned short* __restrict__ VTg, unsigned short* __restrict__ Hc)
{
  __shared__ unsigned short sT[8][64][64];    // tile t = kh*4 + st*2 + isV
  __shared__ float sL[2][4][2][16];

  const int pair = blockIdx.x & 31;           // h = pair&7 -> XCD L2 affinity
  const int b = pair >> 3, h = pair & 7;
  const int qt = blockIdx.x >> 5;
  const int tid = threadIdx.x;
  const int lane = tid & 63, wave = tid >> 6;
  const int l15 = lane & 15, quad = lane >> 4, swl = l15 & 7;
  const int lrow = lane >> 3;
  const int lc8 = ((lane & 7) ^ (lrow & 7)) * 8;
  const int qg = wave & 3, kh = wave >> 2;
  const int qbase = qt * 64 + qg * 16;
  const float S2 = 0.125f * 1.44269504f;      // scale * log2(e)

  const unsigned short* kgp[2];
  const unsigned short* vgp[2];
#pragma unroll
  for (int st = 0; st < 2; st++) {
    kgp[st] = Kg + (size_t)((b * 2 + st) * 1024) * 512 + h * 64;
    vgp[st] = VTg + (size_t)(((b * 2 + st) * 8 + h) * 64) * 1024;
  }

  // Q fragments, both directions, held for the whole kernel
  v8bf qf[2][2];
#pragma unroll
  for (int d = 0; d < 2; d++)
#pragma unroll
    for (int s = 0; s < 2; s++) {
      int qrow = (b * 2 + d) * 1024 + qbase + l15;
      qf[d][s] = ldfrag(&Qg[(size_t)qrow * 512 + h * 64 + s * 32 + quad * 8]);
    }

  // ---------------- pass A: partial l sums (K tiles only) ----------------
  float lacc[2] = {0.f, 0.f};
  {
    // wave w stages half of K-tile (w>>1)*2: chunks c0..c0+3
    const int tA = (wave >> 1) * 2;
    const int stA = (wave >> 1) & 1, khA = wave >> 2;
    const int c0 = (wave & 1) * 4;
    const unsigned short* gA = kgp[stA] + (size_t)(khA * 512 + c0 * 8 + lrow) * 512 + lc8;
    unsigned short* lA = &sT[tA][c0 * 8][0];

    for (int kt = 0; kt < 8; kt++) {
      __syncthreads();
#pragma unroll
      for (int c = 0; c < 4; c++)
        g2l(gA + (size_t)(kt * 64 + c * 8) * 512, lA + c * 512);
      __syncthreads();
      v4f acc[2][4] = {};
#pragma unroll
      for (int s = 0; s < 2; s++)
#pragma unroll
        for (int d = 0; d < 2; d++)
#pragma unroll
          for (int j = 0; j < 4; j++) {
            v8bf kf = ldfrag(&sT[kh * 4 + (1 - d) * 2][j * 16 + l15][((s * 4 + quad) ^ swl) * 8]);
            acc[d][j] = MFMA32(kf, qf[d][s], acc[d][j]);
          }
#pragma unroll
      for (int d = 0; d < 2; d++)
#pragma unroll
        for (int j = 0; j < 4; j++)
#pragma unroll
          for (int r = 0; r < 4; r++)
            lacc[d] += fexp2(acc[d][j][r] * S2);
    }
  }
  // merge partial l over quads, then over kh via sL
#pragma unroll
  for (int d = 0; d < 2; d++) {
    float v = lacc[d];
    v += __shfl_xor(v, 16);
    v += __shfl_xor(v, 32);
    if (quad == 0) sL[kh][qg][d][l15] = v;
  }
  __syncthreads();
  float ll[2];
#pragma unroll
  for (int d = 0; d < 2; d++)
    ll[d] = __log2f(sL[0][qg][d][l15] + sL[1][qg][d][l15]);
  const float dll = ll[0] - ll[1];

  // ---------------- pass B: combine + PV (partial over kh) ----------------
  v4f oacc[2][4] = {};
  {
    // wave w stages tile t = w entirely (8 chunks)
    const int stw = (wave >> 1) & 1, khw = wave >> 2;
    const bool isV = wave & 1;
    const unsigned short* gB;
    size_t cstep, ktstep;
    if (isV) {
      gB = vgp[stw] + (size_t)lrow * 1024 + khw * 512 + lc8;
      cstep = (size_t)8 * 1024;
      ktstep = 64;
    } else {
      gB = kgp[stw] + (size_t)(khw * 512 + lrow) * 512 + lc8;
      cstep = (size_t)8 * 512;
      ktstep = (size_t)64 * 512;
    }
    unsigned short* lB = &sT[wave][0][0];

    for (int kt = 0; kt < 8; kt++) {
      __syncthreads();                        // prev compute done
#pragma unroll
      for (int c = 0; c < 8; c++)
        g2l(gB + (size_t)kt * ktstep + c * cstep, lB + c * 512);
      __syncthreads();                        // tiles ready

      v4f acc[2][4] = {};
#pragma unroll
      for (int s = 0; s < 2; s++)
#pragma unroll
        for (int d = 0; d < 2; d++)
#pragma unroll
          for (int j = 0; j < 4; j++) {
            v8bf kf = ldfrag(&sT[kh * 4 + (1 - d) * 2][j * 16 + l15][((s * 4 + quad) ^ swl) * 8]);
            acc[d][j] = MFMA32(kf, qf[d][s], acc[d][j]);
          }

#pragma unroll
      for (int j = 0; j < 4; j++) {
        float r0[4], r1[4];
#pragma unroll
        for (int r = 0; r < 4; r++) {
          float t = fmaf(acc[1][j][r] - acc[0][j][r], S2, dll);
          float ri = __builtin_amdgcn_rcpf(1.f + fexp2(t));
          r0[r] = ri;
          r1[r] = 1.f - ri;
        }
#if HAVE_MFMA16
        uint2 w0, w1;
        w0.x = pkbf(r0[0], r0[1]); w0.y = pkbf(r0[2], r0[3]);
        w1.x = pkbf(r1[0], r1[1]); w1.y = pkbf(r1[2], r1[3]);
        v4s af0 = __builtin_bit_cast(v4s, w0);
        v4s af1 = __builtin_bit_cast(v4s, w1);
        int vcol = ((j * 2 + (quad >> 1)) ^ swl) * 8 + (quad & 1) * 4;
#pragma unroll
        for (int nt = 0; nt < 4; nt++) {
          v4s vf0 = ld4s(&sT[kh * 4 + 3][nt * 16 + l15][vcol]);   // V of stream 1 (d=0 uses 1-d=1)
          v4s vf1 = ld4s(&sT[kh * 4 + 1][nt * 16 + l15][vcol]);   // V of stream 0
          oacc[0][nt] = MFMA16(af0, vf0, oacc[0][nt]);
          oacc[1][nt] = MFMA16(af1, vf1, oacc[1][nt]);
        }
#else
#pragma unroll
        for (int d = 0; d < 2; d++) {
          float (&cb)[4] = (d == 0) ? r0 : r1;
          v8bf a;
#pragma unroll
          for (int jj = 0; jj < 8; jj++) {
            int src = l15 + 16 * ((jj >> 2) + (quad & 1) * 2);
            float v = __shfl(cb[jj & 3], src);
            a[jj] = __builtin_bit_cast(__bf16, f2bf(v));
          }
#pragma unroll
          for (int nt = 0; nt < 4; nt++) {
            v8bf vf = ldfrag(&sT[kh * 4 + (1 - d) * 2 + 1][nt * 16 + l15]
                               [(((j & 2) * 2 + quad) ^ swl) * 8]);
            oacc[d][nt] = MFMA32(a, vf, oacc[d][nt]);
          }
        }
#endif
      }
    }
  }

  // ---------------- merge kh partials, store ----------------
  __syncthreads();
  float* sO = (float*)&sT[0][0][0];           // 32 KB reuse
  if (kh == 1) {
#pragma unroll
    for (int d = 0; d < 2; d++)
#pragma unroll
      for (int nt = 0; nt < 4; nt++)
#pragma unroll
        for (int r = 0; r < 4; r++)
          sO[(size_t)((d * 4 + nt) * 4 + r) * 256 + qg * 64 + lane] = oacc[d][nt][r];
  }
  __syncthreads();
  if (kh == 0) {
#pragma unroll
    for (int d = 0; d < 2; d++)
#pragma unroll
      for (int nt = 0; nt < 4; nt++)
#pragma unroll
        for (int r = 0; r < 4; r++) {
          float v = oacc[d][nt][r] + sO[(size_t)((d * 4 + nt) * 4 + r) * 256 + qg * 64 + lane];
          int row = (b * 2 + d) * 1024 + qbase + quad * 4 + r;
          int col = h * 64 + nt * 16 + l15;
          Hc[(size_t)row * 512 + col] = f2bf(v);
        }
  }
}

// ---------------------------------------------------------------------------
// LayerNorm (over D=512) + gate + residual.  One WAVE per row (no LDS).
// ---------------------------------------------------------------------------
__global__ __launch_bounds__(256) void ln_kernel(
    const unsigned short* __restrict__ Pb, const float* __restrict__ hidden,
    const float* __restrict__ ln_g, const float* __restrict__ ln_b,
    const float* __restrict__ gate, float* __restrict__ out)
{
  const int row = blockIdx.x * 4 + (threadIdx.x >> 6);
  const int s = (row >> 10) & 1;
  const int lane = threadIdx.x & 63;
  const int d0 = lane * 8;

  uint4 up = *(const uint4*)&Pb[(size_t)row * 512 + d0];
  float x[8] = { lo2f(up.x), hi2f(up.x), lo2f(up.y), hi2f(up.y),
                 lo2f(up.z), hi2f(up.z), lo2f(up.w), hi2f(up.w) };
  float s1 = 0.f, s2 = 0.f;
#pragma unroll
  for (int i = 0; i < 8; i++) { s1 += x[i]; s2 += x[i] * x[i]; }
#pragma unroll
  for (int m = 1; m < 64; m <<= 1) { s1 += __shfl_xor(s1, m); s2 += __shfl_xor(s2, m); }
  float mu = s1 * (1.f / 512.f);
  float var = s2 * (1.f / 512.f) - mu * mu;
  float rs = rsqrtf(var + 1e-5f);
  float al = gate[s];

  float4 h0 = *(const float4*)&hidden[(size_t)row * 512 + d0];
  float4 h1 = *(const float4*)&hidden[(size_t)row * 512 + d0 + 4];
  float4 g0 = *(const float4*)&ln_g[s * 512 + d0];
  float4 g1 = *(const float4*)&ln_g[s * 512 + d0 + 4];
  float4 bb0 = *(const float4*)&ln_b[s * 512 + d0];
  float4 bb1 = *(const float4*)&ln_b[s * 512 + d0 + 4];
  float4 o0, o1;
  o0.x = h0.x + ((x[0] - mu) * rs * g0.x + bb0.x) * al;
  o0.y = h0.y + ((x[1] - mu) * rs * g0.y + bb0.y) * al;
  o0.z = h0.z + ((x[2] - mu) * rs * g0.z + bb0.z) * al;
  o0.w = h0.w + ((x[3] - mu) * rs * g0.w + bb0.w) * al;
  o1.x = h1.x + ((x[4] - mu) * rs * g1.x + bb1.x) * al;
  o1.y = h1.y + ((x[5] - mu) * rs * g1.y + bb1.y) * al;
  o1.z = h1.z + ((x[6] - mu) * rs * g1.z + bb1.z) * al;
  o1.w = h1.w + ((x[7] - mu) * rs * g1.w + bb1.w) * al;
  *(float4*)&out[(size_t)row * 512 + d0] = o0;
  *(float4*)&out[(size_t)row * 512 + d0 + 4] = o1;
}

// ---------------------------------------------------------------------------
extern "C" void kernel_launch(void* const* d_in, const int* in_sizes, int n_in,
                              void* d_out, int out_size, void* d_ws, size_t ws_size,
                              hipStream_t stream)
{
  const float* hidden = (const float*)d_in[0];
  const float* Wq = (const float*)d_in[1];
  const float* bq = (const float*)d_in[2];
  const float* Wk = (const float*)d_in[3];
  const float* bk = (const float*)d_in[4];
  const float* Wv = (const float*)d_in[5];
  const float* bv = (const float*)d_in[6];
  const float* Wo = (const float*)d_in[7];
  const float* bo = (const float*)d_in[8];
  const float* ln_g = (const float*)d_in[9];
  const float* ln_b = (const float*)d_in[10];
  const float* gate = (const float*)d_in[11];

  unsigned short* U = (unsigned short*)d_ws;
  unsigned short* Xbf = U;
  unsigned short* Wqb = U + 4194304;
  unsigned short* Wkb = U + 4456448;
  unsigned short* Wvb = U + 4718592;
  unsigned short* Wob = U + 4980736;
  unsigned short* Qg  = U + 5242880;
  unsigned short* Kg  = U + 9437184;
  unsigned short* VT  = U + 13631488;
  unsigned short* Hc  = U + 17825792;
  unsigned short* Pb  = (unsigned short*)((char*)d_ws + 44302336);

  convert_kernel<<<dim3(5120), 256, 0, stream>>>(hidden, Wq, Wk, Wv, Wo, Xbf);
  gemm_bt<0, 128><<<dim3(4, 64, 3), 256, 0, stream>>>(Xbf, Wqb, Wkb, Wvb, bq, bk, bv, Qg, Kg, VT);
  attn_kernel<<<dim3(512), 512, 0, stream>>>(Qg, Kg, VT, Hc);
  gemm_bt<0, 64><<<dim3(4, 128, 1), 256, 0, stream>>>(Hc, Wob, Wob, Wob, bo, bo, bo, Pb, Pb, Pb);
  ln_kernel<<<dim3(2048), 256, 0, stream>>>(Pb, hidden, ln_g, ln_b, gate, (float*)d_out);
}

// Round 9
// 180.710 us; speedup vs baseline: 1.1267x; 1.1267x over previous
//
#include <hip/hip_runtime.h>

#define DEVI __device__ __forceinline__

typedef __bf16 v8bf __attribute__((ext_vector_type(8)));
typedef float  v4f  __attribute__((ext_vector_type(4)));
typedef short  v4s  __attribute__((ext_vector_type(4)));

DEVI unsigned short f2bf(float f) {
  unsigned u = __builtin_bit_cast(unsigned, f);
  u += 0x7fffu + ((u >> 16) & 1u);
  return (unsigned short)(u >> 16);
}
DEVI v4f MFMA32(v8bf a, v8bf b, v4f c) {
  return __builtin_amdgcn_mfma_f32_16x16x32_bf16(a, b, c, 0, 0, 0);
}
DEVI v8bf ldfrag(const unsigned short* p) {
  return __builtin_bit_cast(v8bf, *(const uint4*)p);
}
DEVI v4s ld4s(const unsigned short* p) {
  return __builtin_bit_cast(v4s, *(const uint2*)p);
}
// pack two floats -> two bf16 in one dword (round-half-up + v_perm)
DEVI unsigned pkbf(float lo, float hi) {
  unsigned a = __builtin_bit_cast(unsigned, hi) + 0x8000u;
  unsigned b = __builtin_bit_cast(unsigned, lo) + 0x8000u;
  return __builtin_amdgcn_perm(a, b, 0x07060302u);
}
DEVI float lo2f(unsigned u) { return __builtin_bit_cast(float, u << 16); }
DEVI float hi2f(unsigned u) { return __builtin_bit_cast(float, u & 0xffff0000u); }

#if __has_builtin(__builtin_amdgcn_exp2f)
DEVI float fexp2(float x) { return __builtin_amdgcn_exp2f(x); }
#else
DEVI float fexp2(float x) { return exp2f(x); }
#endif

#if __has_builtin(__builtin_amdgcn_mfma_f32_16x16x16bf16_1k)
#define HAVE_MFMA16 1
DEVI v4f MFMA16(v4s a, v4s b, v4f c) {
  return __builtin_amdgcn_mfma_f32_16x16x16bf16_1k(a, b, c, 0, 0, 0);
}
#else
#define HAVE_MFMA16 0
#endif

// async global->LDS, 16B per lane; per-lane global addresses pre-apply the
// XOR swizzle (LDS side must stay contiguous).
#if __has_builtin(__builtin_amdgcn_global_load_lds)
DEVI void g2l(const unsigned short* g, unsigned short* l) {
  __builtin_amdgcn_global_load_lds(
      (const __attribute__((address_space(1))) unsigned int*)g,
      (__attribute__((address_space(3))) unsigned int*)l, 16, 0, 0);
}
#else
DEVI void g2l(const unsigned short* g, unsigned short* l) {
  *(uint4*)((char*)l + (threadIdx.x & 63) * 16) = *(const uint4*)g;
}
#endif

// ---------------------------------------------------------------------------
// fp32 -> bf16 conversion of X (4,2,1024,512) and Wq/Wk/Wv/Wo (512x512 each).
// ---------------------------------------------------------------------------
__global__ __launch_bounds__(256) void convert_kernel(
    const float* __restrict__ X, const float* __restrict__ Wq,
    const float* __restrict__ Wk, const float* __restrict__ Wv,
    const float* __restrict__ Wo, unsigned short* __restrict__ dst)
{
  int t = blockIdx.x * 256 + threadIdx.x;
  int idx = t * 4;
  const float* src;
  if (idx < 4194304) {
    src = X + idx;
  } else {
    int u = idx - 4194304;
    int w = u >> 18;
    const float* W = (w == 0) ? Wq : (w == 1) ? Wk : (w == 2) ? Wv : Wo;
    src = W + (u & 262143);
  }
  float4 f = *(const float4*)src;
  uint2 o;
  o.x = pkbf(f.x, f.y);
  o.y = pkbf(f.z, f.w);
  *(uint2*)&dst[idx] = o;
}

// ---------------------------------------------------------------------------
// C[m][n] = sum_k A[m][k]*W[n][k] + bias[n]   (BT GEMM, M=8192 N=512 K=512)
// BMx128 tile, 4 waves, global_load_lds staging, XOR-swizzled LDS.
// OUTM=0 bf16 out (z==2 -> V transposed into VT);  OUTM=1 fp32 out.
// ---------------------------------------------------------------------------
template<int OUTM, int BM>
__global__ __launch_bounds__(256) void gemm_bt(
    const unsigned short* __restrict__ A,
    const unsigned short* __restrict__ W0, const unsigned short* __restrict__ W1,
    const unsigned short* __restrict__ W2,
    const float* __restrict__ b0, const float* __restrict__ b1, const float* __restrict__ b2,
    void* __restrict__ C0, void* __restrict__ C1, void* __restrict__ C2)
{
  const int K = 512, N = 512;
  const int MI = BM / 32;
  const int PER = (BM / 8 + 16) / 4;          // g2l chunks per wave
  __shared__ unsigned short sAB[(BM + 128) * 64];
  const int z = blockIdx.z;
  const unsigned short* W = (z == 0) ? W0 : (z == 1) ? W1 : W2;
  const float* bias = (z == 0) ? b0 : (z == 1) ? b1 : b2;
  void* C = (z == 0) ? C0 : (z == 1) ? C1 : C2;

  const int tid = threadIdx.x;
  const int lane = tid & 63, wave = tid >> 6;
  const int l15 = lane & 15, quad = lane >> 4, swl = l15 & 7;
  const int lrow = lane >> 3;
  const int lc8 = ((lane & 7) ^ (lrow & 7)) * 8;
  const int wm = (wave >> 1) * (BM / 2), wn = (wave & 1) * 64;
  const int mbase = blockIdx.y * BM, nbase = blockIdx.x * 128;

  const unsigned short* gsrc[PER];
  unsigned short* ldst[PER];
#pragma unroll
  for (int t = 0; t < PER; t++) {
    int c = wave * PER + t;
    ldst[t] = &sAB[c * 512];
    if (c < BM / 8) gsrc[t] = A + (size_t)(mbase + c * 8 + lrow) * K + lc8;
    else            gsrc[t] = W + (size_t)(nbase + (c - BM / 8) * 8 + lrow) * K + lc8;
  }

  v4f acc[MI][4] = {};

  for (int kt = 0; kt < K; kt += 64) {
    __syncthreads();
#pragma unroll
    for (int t = 0; t < PER; t++) g2l(gsrc[t] + kt, ldst[t]);
    __syncthreads();
#pragma unroll
    for (int s = 0; s < 2; s++) {
      v8bf af[MI], bf[4];
#pragma unroll
      for (int i = 0; i < MI; i++)
        af[i] = ldfrag(&sAB[(wm + i * 16 + l15) * 64 + ((s * 4 + quad) ^ swl) * 8]);
#pragma unroll
      for (int j = 0; j < 4; j++)
        bf[j] = ldfrag(&sAB[(BM + wn + j * 16 + l15) * 64 + ((s * 4 + quad) ^ swl) * 8]);
#pragma unroll
      for (int i = 0; i < MI; i++)
#pragma unroll
        for (int j = 0; j < 4; j++)
          acc[i][j] = MFMA32(af[i], bf[j], acc[i][j]);
    }
  }

#pragma unroll
  for (int i = 0; i < MI; i++)
#pragma unroll
    for (int j = 0; j < 4; j++) {
      int row0 = mbase + wm + i * 16 + quad * 4;
      int col = nbase + wn + j * 16 + l15;
      float v[4];
#pragma unroll
      for (int r = 0; r < 4; r++) v[r] = acc[i][j][r] + bias[col];
      if (OUTM == 1) {
#pragma unroll
        for (int r = 0; r < 4; r++) ((float*)C)[(size_t)(row0 + r) * N + col] = v[r];
      } else if (z == 2) {
        int bs = row0 >> 10, t0 = row0 & 1023;
        int hh = col >> 6, hd = col & 63;
        uint2 o;
        o.x = pkbf(v[0], v[1]);
        o.y = pkbf(v[2], v[3]);
        *(uint2*)&((unsigned short*)C)[(size_t)((bs * 8 + hh) * 64 + hd) * 1024 + t0] = o;
      } else {
#pragma unroll
        for (int r = 0; r < 4; r++)
          ((unsigned short*)C)[(size_t)(row0 + r) * N + col] = f2bf(v[r]);
      }
    }
}

// ---------------------------------------------------------------------------
// Fused competitive cross-attention — round-7 shape + double-buffered LDS.
// Grid 512 x 256 threads (4 waves).  Block = (b,h,64-q-row tile); wave w owns
// q rows [w*16,w*16+16) for BOTH directions (combine in-register, sigmoid
// form: r0 = 1/(1+2^((s1-s0)*S2 + ll0-ll1))).  K/V staged by global_load_lds
// into double-buffered XOR-swizzled tiles; ONE barrier per iteration:
//   barrier -> issue g2l(kt+1 -> other buf) -> compute(kt)
// so the auto vmcnt(0)-before-barrier waits loads that had a full compute
// iteration in flight.  LDS 64 KB, 2 blk/CU.
// ---------------------------------------------------------------------------
__global__ __launch_bounds__(256, 2) void attn_kernel(
    const unsigned short* __restrict__ Qg, const unsigned short* __restrict__ Kg,
    const unsigned short* __restrict__ VTg, unsigned short* __restrict__ Hc)
{
  __shared__ unsigned short sK[2][2][64][64];   // [buf][stream]
  __shared__ unsigned short sV[2][2][64][64];

  const int pair = blockIdx.x & 31;           // h = pair&7 -> XCD L2 affinity
  const int b = pair >> 3, h = pair & 7;
  const int qt = blockIdx.x >> 5;
  const int tid = threadIdx.x;
  const int lane = tid & 63, wave = tid >> 6;
  const int l15 = lane & 15, quad = lane >> 4, swl = l15 & 7;
  const int lrow = lane >> 3;
  const int lc8 = ((lane & 7) ^ (lrow & 7)) * 8;
  const int qbase = qt * 64 + wave * 16;
  const float S2 = 0.125f * 1.44269504f;      // scale * log2(e)

  const unsigned short* kgp[2];
  const unsigned short* vgp[2];
#pragma unroll
  for (int st = 0; st < 2; st++) {
    kgp[st] = Kg + (size_t)((b * 2 + st) * 1024) * 512 + h * 64;
    vgp[st] = VTg + (size_t)(((b * 2 + st) * 8 + h) * 64) * 1024;
  }

  // Q fragments, both directions, held for the whole kernel
  v8bf qf[2][2];
#pragma unroll
  for (int d = 0; d < 2; d++)
#pragma unroll
    for (int s = 0; s < 2; s++) {
      int qrow = (b * 2 + d) * 1024 + qbase + l15;
      qf[d][s] = ldfrag(&Qg[(size_t)qrow * 512 + h * 64 + s * 32 + quad * 8]);
    }

  // ---------------- pass A: l sums (K only, dbuf) ----------------
  float lacc[2] = {0.f, 0.f};
  {
    const unsigned short* gA[4];
    unsigned short* lA[2][4];
#pragma unroll
    for (int t = 0; t < 4; t++) {
      int c = wave * 4 + t;                   // 16 K chunks over 4 waves
      gA[t] = kgp[c >> 3] + (size_t)((c & 7) * 8 + lrow) * 512 + lc8;
      lA[0][t] = &sK[0][c >> 3][(c & 7) * 8][0];
      lA[1][t] = &sK[1][c >> 3][(c & 7) * 8][0];
    }
#pragma unroll
    for (int t = 0; t < 4; t++) g2l(gA[t], lA[0][t]);    // tile 0

    for (int kt = 0; kt < 16; kt++) {
      __syncthreads();                        // tile kt landed; buf free
      if (kt < 15) {
#pragma unroll
        for (int t = 0; t < 4; t++)
          g2l(gA[t] + (size_t)(kt + 1) * 32768, lA[(kt + 1) & 1][t]);
      }
      const int bu = kt & 1;
      v4f acc[2][4] = {};
#pragma unroll
      for (int s = 0; s < 2; s++)
#pragma unroll
        for (int d = 0; d < 2; d++)
#pragma unroll
          for (int j = 0; j < 4; j++) {
            v8bf kf = ldfrag(&sK[bu][1 - d][j * 16 + l15][((s * 4 + quad) ^ swl) * 8]);
            acc[d][j] = MFMA32(kf, qf[d][s], acc[d][j]);
          }
#pragma unroll
      for (int d = 0; d < 2; d++)
#pragma unroll
        for (int j = 0; j < 4; j++)
#pragma unroll
          for (int r = 0; r < 4; r++)
            lacc[d] += fexp2(acc[d][j][r] * S2);
    }
  }
  float ll[2];
#pragma unroll
  for (int d = 0; d < 2; d++) {
    float v = lacc[d];
    v += __shfl_xor(v, 16);
    v += __shfl_xor(v, 32);
    ll[d] = __log2f(v);
  }
  const float dll = ll[0] - ll[1];

  // ---------------- pass B: combine + PV (dbuf) ----------------
  v4f oacc[2][4] = {};
  {
    const unsigned short* gB[8];
    unsigned short* lB[2][8];
    size_t stp[8];
#pragma unroll
    for (int t = 0; t < 8; t++) {
      int c = wave * 8 + t;                   // 16 K + 16 V chunks over 4 waves
      if (c < 16) {
        gB[t] = kgp[c >> 3] + (size_t)((c & 7) * 8 + lrow) * 512 + lc8;
        stp[t] = 32768;
        lB[0][t] = &sK[0][c >> 3][(c & 7) * 8][0];
        lB[1][t] = &sK[1][c >> 3][(c & 7) * 8][0];
      } else {
        int cv = c - 16;
        gB[t] = vgp[cv >> 3] + (size_t)((cv & 7) * 8 + lrow) * 1024 + lc8;
        stp[t] = 64;
        lB[0][t] = &sV[0][cv >> 3][(cv & 7) * 8][0];
        lB[1][t] = &sV[1][cv >> 3][(cv & 7) * 8][0];
      }
    }
    __syncthreads();                          // pass A reads done
#pragma unroll
    for (int t = 0; t < 8; t++) g2l(gB[t], lB[0][t]);    // tile 0

    for (int kt = 0; kt < 16; kt++) {
      __syncthreads();                        // tile kt landed; other buf free
      if (kt < 15) {
#pragma unroll
        for (int t = 0; t < 8; t++)
          g2l(gB[t] + (size_t)(kt + 1) * stp[t], lB[(kt + 1) & 1][t]);
      }
      const int bu = kt & 1;

      v4f acc[2][4] = {};
#pragma unroll
      for (int s = 0; s < 2; s++)
#pragma unroll
        for (int d = 0; d < 2; d++)
#pragma unroll
          for (int j = 0; j < 4; j++) {
            v8bf kf = ldfrag(&sK[bu][1 - d][j * 16 + l15][((s * 4 + quad) ^ swl) * 8]);
            acc[d][j] = MFMA32(kf, qf[d][s], acc[d][j]);
          }

#pragma unroll
      for (int j = 0; j < 4; j++) {
        float r0[4], r1[4];
#pragma unroll
        for (int r = 0; r < 4; r++) {
          float t = fmaf(acc[1][j][r] - acc[0][j][r], S2, dll);
          float ri = __builtin_amdgcn_rcpf(1.f + fexp2(t));
          r0[r] = ri;
          r1[r] = 1.f - ri;
        }
#if HAVE_MFMA16
        uint2 w0, w1;
        w0.x = pkbf(r0[0], r0[1]); w0.y = pkbf(r0[2], r0[3]);
        w1.x = pkbf(r1[0], r1[1]); w1.y = pkbf(r1[2], r1[3]);
        v4s af0 = __builtin_bit_cast(v4s, w0);
        v4s af1 = __builtin_bit_cast(v4s, w1);
        int vcol = ((j * 2 + (quad >> 1)) ^ swl) * 8 + (quad & 1) * 4;
#pragma unroll
        for (int nt = 0; nt < 4; nt++) {
          v4s vf0 = ld4s(&sV[bu][1][nt * 16 + l15][vcol]);
          v4s vf1 = ld4s(&sV[bu][0][nt * 16 + l15][vcol]);
          oacc[0][nt] = MFMA16(af0, vf0, oacc[0][nt]);
          oacc[1][nt] = MFMA16(af1, vf1, oacc[1][nt]);
        }
#else
#pragma unroll
        for (int d = 0; d < 2; d++) {
          float (&cb)[4] = (d == 0) ? r0 : r1;
          v8bf a;
#pragma unroll
          for (int jj = 0; jj < 8; jj++) {
            int src = l15 + 16 * ((jj >> 2) + (quad & 1) * 2);
            float v = __shfl(cb[jj & 3], src);
            a[jj] = __builtin_bit_cast(__bf16, f2bf(v));
          }
#pragma unroll
          for (int nt = 0; nt < 4; nt++) {
            v8bf vf = ldfrag(&sV[bu][1 - d][nt * 16 + l15]
                               [(((j & 2) * 2 + quad) ^ swl) * 8]);
            oacc[d][nt] = MFMA32(a, vf, oacc[d][nt]);
          }
        }
#endif
      }
    }
  }

#pragma unroll
  for (int d = 0; d < 2; d++)
#pragma unroll
    for (int nt = 0; nt < 4; nt++)
#pragma unroll
      for (int r = 0; r < 4; r++) {
        int row = (b * 2 + d) * 1024 + qbase + quad * 4 + r;
        int col = h * 64 + nt * 16 + l15;
        Hc[(size_t)row * 512 + col] = f2bf(oacc[d][nt][r]);
      }
}

// ---------------------------------------------------------------------------
// LayerNorm (over D=512) + gate + residual.  One WAVE per row (no LDS).
// ---------------------------------------------------------------------------
__global__ __launch_bounds__(256) void ln_kernel(
    const unsigned short* __restrict__ Pb, const float* __restrict__ hidden,
    const float* __restrict__ ln_g, const float* __restrict__ ln_b,
    const float* __restrict__ gate, float* __restrict__ out)
{
  const int row = blockIdx.x * 4 + (threadIdx.x >> 6);
  const int s = (row >> 10) & 1;
  const int lane = threadIdx.x & 63;
  const int d0 = lane * 8;

  uint4 up = *(const uint4*)&Pb[(size_t)row * 512 + d0];
  float x[8] = { lo2f(up.x), hi2f(up.x), lo2f(up.y), hi2f(up.y),
                 lo2f(up.z), hi2f(up.z), lo2f(up.w), hi2f(up.w) };
  float s1 = 0.f, s2 = 0.f;
#pragma unroll
  for (int i = 0; i < 8; i++) { s1 += x[i]; s2 += x[i] * x[i]; }
#pragma unroll
  for (int m = 1; m < 64; m <<= 1) { s1 += __shfl_xor(s1, m); s2 += __shfl_xor(s2, m); }
  float mu = s1 * (1.f / 512.f);
  float var = s2 * (1.f / 512.f) - mu * mu;
  float rs = rsqrtf(var + 1e-5f);
  float al = gate[s];

  float4 h0 = *(const float4*)&hidden[(size_t)row * 512 + d0];
  float4 h1 = *(const float4*)&hidden[(size_t)row * 512 + d0 + 4];
  float4 g0 = *(const float4*)&ln_g[s * 512 + d0];
  float4 g1 = *(const float4*)&ln_g[s * 512 + d0 + 4];
  float4 bb0 = *(const float4*)&ln_b[s * 512 + d0];
  float4 bb1 = *(const float4*)&ln_b[s * 512 + d0 + 4];
  float4 o0, o1;
  o0.x = h0.x + ((x[0] - mu) * rs * g0.x + bb0.x) * al;
  o0.y = h0.y + ((x[1] - mu) * rs * g0.y + bb0.y) * al;
  o0.z = h0.z + ((x[2] - mu) * rs * g0.z + bb0.z) * al;
  o0.w = h0.w + ((x[3] - mu) * rs * g0.w + bb0.w) * al;
  o1.x = h1.x + ((x[4] - mu) * rs * g1.x + bb1.x) * al;
  o1.y = h1.y + ((x[5] - mu) * rs * g1.y + bb1.y) * al;
  o1.z = h1.z + ((x[6] - mu) * rs * g1.z + bb1.z) * al;
  o1.w = h1.w + ((x[7] - mu) * rs * g1.w + bb1.w) * al;
  *(float4*)&out[(size_t)row * 512 + d0] = o0;
  *(float4*)&out[(size_t)row * 512 + d0 + 4] = o1;
}

// ---------------------------------------------------------------------------
extern "C" void kernel_launch(void* const* d_in, const int* in_sizes, int n_in,
                              void* d_out, int out_size, void* d_ws, size_t ws_size,
                              hipStream_t stream)
{
  const float* hidden = (const float*)d_in[0];
  const float* Wq = (const float*)d_in[1];
  const float* bq = (const float*)d_in[2];
  const float* Wk = (const float*)d_in[3];
  const float* bk = (const float*)d_in[4];
  const float* Wv = (const float*)d_in[5];
  const float* bv = (const float*)d_in[6];
  const float* Wo = (const float*)d_in[7];
  const float* bo = (const float*)d_in[8];
  const float* ln_g = (const float*)d_in[9];
  const float* ln_b = (const float*)d_in[10];
  const float* gate = (const float*)d_in[11];

  unsigned short* U = (unsigned short*)d_ws;
  unsigned short* Xbf = U;
  unsigned short* Wqb = U + 4194304;
  unsigned short* Wkb = U + 4456448;
  unsigned short* Wvb = U + 4718592;
  unsigned short* Wob = U + 4980736;
  unsigned short* Qg  = U + 5242880;
  unsigned short* Kg  = U + 9437184;
  unsigned short* VT  = U + 13631488;
  unsigned short* Hc  = U + 17825792;
  unsigned short* Pb  = (unsigned short*)((char*)d_ws + 44302336);

  convert_kernel<<<dim3(5120), 256, 0, stream>>>(hidden, Wq, Wk, Wv, Wo, Xbf);
  gemm_bt<0, 128><<<dim3(4, 64, 3), 256, 0, stream>>>(Xbf, Wqb, Wkb, Wvb, bq, bk, bv, Qg, Kg, VT);
  attn_kernel<<<dim3(512), 256, 0, stream>>>(Qg, Kg, VT, Hc);
  gemm_bt<0, 64><<<dim3(4, 128, 1), 256, 0, stream>>>(Hc, Wob, Wob, Wob, bo, bo, bo, Pb, Pb, Pb);
  ln_kernel<<<dim3(2048), 256, 0, stream>>>(Pb, hidden, ln_g, ln_b, gate, (float*)d_out);
}